// Round 5
// baseline (559.684 us; speedup 1.0000x reference)
//
#include <hip/hip_runtime.h>
#include <math.h>

// (B, T, D, H, L) = (8, 512, 128, 128, 2). All fp32 I/O.
#define BB 8
#define TT 512
#define DD 128
#define HH 128
#define BT_ (BB * TT)                 // 4096
static const size_t BTH = (size_t)BT_ * HH;  // 524288

#define AS1 __attribute__((address_space(1)))
#define AS3 __attribute__((address_space(3)))

// act planes (all planar [row][h]): 0=q 1=k 2=v 3=i 4=f 5=o
// hbuf = act + 6*BTH. Wt (12x128x128) in d_out, consumed before final scan.

struct WArgs { const float* W[6]; };
struct BArgs { const float* b[6]; };

template <int CTRL>
__device__ __forceinline__ float dpp_add(float x) {
  int y = __builtin_amdgcn_update_dpp(0, __builtin_bit_cast(int, x), CTRL,
                                      0xF, 0xF, true);
  return x + __builtin_bit_cast(float, y);
}

// ---------------------------------------------------------------------------
// Transpose all 12 weight slabs: Wt[l*6+p][d][h] = W_p[l][h][d].
// ---------------------------------------------------------------------------
__global__ __launch_bounds__(256)
void transpose_w(WArgs w, float* __restrict__ Wt) {
  __shared__ float t[32][33];
  const int l = blockIdx.y / 6, p = blockIdx.y % 6;
  const float* src = w.W[p] + (size_t)l * HH * DD;
  float* dst = Wt + (size_t)blockIdx.y * HH * DD;
  const int ty0 = (blockIdx.x >> 2) * 32, tx0 = (blockIdx.x & 3) * 32;
  const int tx = threadIdx.x & 31, ty = threadIdx.x >> 5;
#pragma unroll
  for (int j = 0; j < 32; j += 8)
    t[ty + j][tx] = src[(size_t)(ty0 + ty + j) * DD + tx0 + tx];
  __syncthreads();
#pragma unroll
  for (int j = 0; j < 32; j += 8)
    dst[(size_t)(tx0 + ty + j) * HH + ty0 + tx] = t[tx][ty + j];
}

// ---------------------------------------------------------------------------
// Projection: act[p][row][h] = act_p( sum_d X[row][d] * Wt_p[d][h] + b_p[h] )
// grid (BT_/32, 6), block 256. Thread = 2 rows x 8 h. Planar float4 stores.
// ---------------------------------------------------------------------------
__global__ __launch_bounds__(256)
void proj_kernel(const float* __restrict__ X, const float* __restrict__ Wtl,
                 BArgs args, float* __restrict__ act) {
  __shared__ float xs[32][132];
  const int p = blockIdx.y;
  const int row0 = blockIdx.x * 32;
  const int tid = threadIdx.x;
  {
    const float4* xg = (const float4*)(X + (size_t)row0 * DD);
#pragma unroll
    for (int i = 0; i < 4; ++i) {
      int u = tid + 256 * i;
      float4 v = xg[u];
      *(float4*)&xs[u >> 5][(u & 31) * 4] = v;
    }
  }
  __syncthreads();

  const int h0 = (tid & 15) * 8;
  const int r0 = (tid >> 4) * 2;
  const float* wtp = Wtl + (size_t)p * HH * DD;

  float acc[2][8];
#pragma unroll
  for (int r = 0; r < 2; ++r)
#pragma unroll
    for (int j = 0; j < 8; ++j) acc[r][j] = 0.f;

  for (int d0 = 0; d0 < DD; d0 += 4) {
    float4 wa[4], wb[4];
#pragma unroll
    for (int i = 0; i < 4; ++i) {
      wa[i] = *(const float4*)(wtp + (size_t)(d0 + i) * HH + h0);
      wb[i] = *(const float4*)(wtp + (size_t)(d0 + i) * HH + h0 + 4);
    }
    float4 x0 = *(const float4*)&xs[r0][d0];
    float4 x1 = *(const float4*)&xs[r0 + 1][d0];
    const float xa[4] = {x0.x, x0.y, x0.z, x0.w};
    const float xb[4] = {x1.x, x1.y, x1.z, x1.w};
#pragma unroll
    for (int i = 0; i < 4; ++i) {
      acc[0][0] = fmaf(xa[i], wa[i].x, acc[0][0]);
      acc[0][1] = fmaf(xa[i], wa[i].y, acc[0][1]);
      acc[0][2] = fmaf(xa[i], wa[i].z, acc[0][2]);
      acc[0][3] = fmaf(xa[i], wa[i].w, acc[0][3]);
      acc[0][4] = fmaf(xa[i], wb[i].x, acc[0][4]);
      acc[0][5] = fmaf(xa[i], wb[i].y, acc[0][5]);
      acc[0][6] = fmaf(xa[i], wb[i].z, acc[0][6]);
      acc[0][7] = fmaf(xa[i], wb[i].w, acc[0][7]);
      acc[1][0] = fmaf(xb[i], wa[i].x, acc[1][0]);
      acc[1][1] = fmaf(xb[i], wa[i].y, acc[1][1]);
      acc[1][2] = fmaf(xb[i], wa[i].z, acc[1][2]);
      acc[1][3] = fmaf(xb[i], wa[i].w, acc[1][3]);
      acc[1][4] = fmaf(xb[i], wb[i].x, acc[1][4]);
      acc[1][5] = fmaf(xb[i], wb[i].y, acc[1][5]);
      acc[1][6] = fmaf(xb[i], wb[i].z, acc[1][6]);
      acc[1][7] = fmaf(xb[i], wb[i].w, acc[1][7]);
    }
  }

  const float4 b0 = *(const float4*)(args.b[p] + h0);
  const float4 b1 = *(const float4*)(args.b[p] + h0 + 4);
  const float bias[8] = {b0.x, b0.y, b0.z, b0.w, b1.x, b1.y, b1.z, b1.w};
#pragma unroll
  for (int r = 0; r < 2; ++r) {
    const size_t row = (size_t)row0 + r0 + r;
    float v[8];
#pragma unroll
    for (int j = 0; j < 8; ++j) {
      float a = acc[r][j] + bias[j];
      if (p == 1)      a *= 0.088388347648318447f;   // 1/sqrt(128)
      else if (p == 3) a = __expf(a);
      else if (p >= 4) a = 1.0f / (1.0f + __expf(-a));
      v[j] = a;
    }
    float* dst = act + (size_t)p * BTH + row * HH + h0;
    *(float4*)dst = make_float4(v[0], v[1], v[2], v[3]);
    *(float4*)(dst + 4) = make_float4(v[4], v[5], v[6], v[7]);
  }
}

// ---------------------------------------------------------------------------
// Scan: sequential over T. 256 single-wave blocks; b = blockIdx&7 (XCD-local).
// LDS ring of 8 pair-slots (pair = 2 timesteps); each slot holds rows of all
// 6 planes (q,k,i,f,v,o: 256 floats each = 6KB). Prefetched 6 pairs ahead via
// global_load_lds (1KB DMA per plane-pair), drained with manual vmcnt(36) —
// the loop body contains NO other vmem ops (h staged in LDS via ds_write,
// flushed at the end), so the count is static.
// Lane: r=lane>>4 -> row sl*4+r; g=lane&15 -> cols 8g..8g+8 (C[8]).
// n owned at cols 2*lane, 2*lane+1. h uses OLD C, OLD n (per reference).
// ---------------------------------------------------------------------------
#define RING_PAIRS 8
#define PF_DIST 6
#define SLOT_F 1536   // 6 planes * 256 floats
#define HSTAGE (RING_PAIRS * SLOT_F)

__global__ __launch_bounds__(64)
void scan_kernel(const float* __restrict__ act, float* __restrict__ hout) {
  __shared__ float smem[RING_PAIRS * SLOT_F + TT * 4];  // 48KB ring + 8KB h
  const int lane = threadIdx.x;
  const int b = blockIdx.x & 7;
  const int sl = blockIdx.x >> 3;
  const int r = lane >> 4;
  const int g = lane & 15;
  const int irow = sl * 4 + r;
  const size_t boff = (size_t)b * TT * HH;
  const float* qp = act + boff;
  const float* kp = act + BTH + boff;
  const float* vp = act + 2 * BTH + boff;
  const float* ip = act + 3 * BTH + boff;
  const float* fp = act + 4 * BTH + boff;
  const float* op = act + 5 * BTH + boff;

  float C[8];
#pragma unroll
  for (int c = 0; c < 8; ++c) C[c] = 0.f;
  float nx = 0.f, ny = 0.f;

  // DMA one plane-pair (2 rows = 1KB) into LDS: dst uniform, lane*16 implicit.
  auto pf = [&](const float* src, float* ldsbase) {
    __builtin_amdgcn_global_load_lds((const AS1 void*)src,
                                     (AS3 void*)ldsbase, 16, 0, 0);
  };
  auto prefetch_pair = [&](int p) {
    float* sb = &smem[(p & (RING_PAIRS - 1)) * SLOT_F];
    const size_t o = (size_t)p * 256 + 4 * lane;
    pf(qp + o, sb);
    pf(kp + o, sb + 256);
    pf(ip + o, sb + 512);
    pf(fp + o, sb + 768);
    pf(vp + o, sb + 1024);
    pf(op + o, sb + 1280);
  };

  auto step = [&](const float* sb, int t) {
    const int e = (t & 1) * 128;
    const float4 q0 = *(const float4*)(sb + e + 8 * g);
    const float4 q1 = *(const float4*)(sb + e + 8 * g + 4);
    const float4 k0 = *(const float4*)(sb + 256 + e + 8 * g);
    const float4 k1 = *(const float4*)(sb + 256 + e + 8 * g + 4);
    const float2 in2 = *(const float2*)(sb + 512 + e + 2 * lane);
    const float2 fn2 = *(const float2*)(sb + 768 + e + 2 * lane);
    const float2 qn2 = *(const float2*)(sb + e + 2 * lane);
    const float2 kn2 = *(const float2*)(sb + 256 + e + 2 * lane);
    const float ir = sb[512 + e + irow];
    const float fr = sb[768 + e + irow];
    const float vr = sb[1024 + e + irow];
    const float og = sb[1280 + e + irow];

    // denom from OLD n: 64-lane DPP sum -> lane 63 -> SGPR broadcast
    float dp = fmaf(nx, qn2.x, ny * qn2.y);
    dp = dpp_add<0x111>(dp);
    dp = dpp_add<0x112>(dp);
    dp = dpp_add<0x114>(dp);
    dp = dpp_add<0x118>(dp);
    dp = dpp_add<0x142>(dp);
    dp = dpp_add<0x143>(dp);
    const float dpv = __builtin_bit_cast(
        float, __builtin_amdgcn_readlane(__builtin_bit_cast(int, dp), 63));
    const float inv = __builtin_amdgcn_rcpf(fmaxf(fabsf(dpv), 1.0f));

    // h_tilde from OLD C
    float acc = 0.f;
    acc = fmaf(C[0], q0.x, acc); acc = fmaf(C[1], q0.y, acc);
    acc = fmaf(C[2], q0.z, acc); acc = fmaf(C[3], q0.w, acc);
    acc = fmaf(C[4], q1.x, acc); acc = fmaf(C[5], q1.y, acc);
    acc = fmaf(C[6], q1.z, acc); acc = fmaf(C[7], q1.w, acc);
    acc = dpp_add<0x111>(acc);
    acc = dpp_add<0x112>(acc);
    acc = dpp_add<0x114>(acc);
    acc = dpp_add<0x118>(acc);
    if (g == 15) smem[HSTAGE + t * 4 + r] = og * acc * inv;  // ds_write (lgkm)

    // n update
    nx = fmaf(fn2.x, nx, in2.x * kn2.x);
    ny = fmaf(fn2.y, ny, in2.y * kn2.y);

    // C update: C = f[row]*C + (i[row]*v[row])*k[col]
    const float ar = ir * vr;
    C[0] = fmaf(fr, C[0], ar * k0.x); C[1] = fmaf(fr, C[1], ar * k0.y);
    C[2] = fmaf(fr, C[2], ar * k0.z); C[3] = fmaf(fr, C[3], ar * k0.w);
    C[4] = fmaf(fr, C[4], ar * k1.x); C[5] = fmaf(fr, C[5], ar * k1.y);
    C[6] = fmaf(fr, C[6], ar * k1.z); C[7] = fmaf(fr, C[7], ar * k1.w);
  };

#pragma unroll 1
  for (int p = 0; p < PF_DIST; ++p) prefetch_pair(p);

#pragma unroll 1
  for (int p = 0; p < TT / 2; ++p) {
    prefetch_pair(p + PF_DIST);
    // wait until pair p's 6 DMAs retired: <= 6*PF_DIST newer events in flight
    __builtin_amdgcn_s_waitcnt(0x8F74);  // vmcnt(36), lgkm/exp ignored
    __builtin_amdgcn_sched_barrier(0);
    const float* sb = &smem[(p & (RING_PAIRS - 1)) * SLOT_F];
    step(sb, 2 * p);
    step(sb, 2 * p + 1);
  }

  __builtin_amdgcn_s_waitcnt(0x0F70);  // drain all DMAs (tail prefetches)
  __syncthreads();

  // flush h: 2048 floats -> global
  float* hst = &smem[HSTAGE];
#pragma unroll 1
  for (int idx = lane; idx < TT * 4; idx += 64) {
    const int t = idx >> 2, rr = idx & 3;
    hout[((size_t)b * TT + t) * HH + sl * 4 + rr] = hst[idx];
  }
}

// ---------------------------------------------------------------------------
extern "C" void kernel_launch(void* const* d_in, const int* in_sizes, int n_in,
                              void* d_out, int out_size, void* d_ws,
                              size_t ws_size, hipStream_t stream) {
  (void)in_sizes; (void)n_in; (void)out_size; (void)ws_size;
  const float* x = (const float*)d_in[0];
  float* act = (float*)d_ws;            // 6 * BTH floats
  float* hbuf = act + 6 * BTH;          // BTH floats
  float* Wt = (float*)d_out;            // 12*128*128 floats, overwritten later

  WArgs wa;
  for (int j = 0; j < 6; ++j) wa.W[j] = (const float*)d_in[1 + j];
  transpose_w<<<dim3(16, 12), 256, 0, stream>>>(wa, Wt);

  for (int l = 0; l < 2; ++l) {
    BArgs ba;
    for (int j = 0; j < 6; ++j)
      ba.b[j] = (const float*)d_in[7 + j] + (size_t)l * HH;
    const float* wtl = Wt + (size_t)l * 6 * HH * DD;
    const float* xin = (l == 0) ? x : hbuf;
    float* hdst = (l == 0) ? hbuf : (float*)d_out;
    proj_kernel<<<dim3(BT_ / 32, 6), 256, 0, stream>>>(xin, wtl, ba, act);
    scan_kernel<<<256, 64, 0, stream>>>(act, hdst);
  }
}

// Round 6
// 404.871 us; speedup vs baseline: 1.3824x; 1.3824x over previous
//
#include <hip/hip_runtime.h>
#include <math.h>

// (B, T, D, H, L) = (8, 512, 128, 128, 2). All fp32 I/O.
#define BB 8
#define TT 512
#define DD 128
#define HH 128
#define BT_ (BB * TT)                 // 4096
static const size_t BTH = (size_t)BT_ * HH;  // 524288

// act planes (all planar [row][h]): 0=q 1=k 2=v 3=i 4=f 5=o
// hbuf = act + 6*BTH (layer-1 output). Wt (12x128x128) lives in d_out's
// first 196608 floats; consumed by both proj dispatches, then fully
// overwritten by the final scan (stream-ordered, safe).

struct WArgs { const float* W[6]; };
struct BArgs { const float* b[6]; };

template <int CTRL>
__device__ __forceinline__ float dpp_add(float x) {
  int y = __builtin_amdgcn_update_dpp(0, __builtin_bit_cast(int, x), CTRL,
                                      0xF, 0xF, true);
  return x + __builtin_bit_cast(float, y);
}

// ---------------------------------------------------------------------------
// Transpose all 12 weight slabs: Wt[l*6+p][d][h] = W_p[l][h][d].
// ---------------------------------------------------------------------------
__global__ __launch_bounds__(256)
void transpose_w(WArgs w, float* __restrict__ Wt) {
  __shared__ float t[32][33];
  const int l = blockIdx.y / 6, p = blockIdx.y % 6;
  const float* src = w.W[p] + (size_t)l * HH * DD;
  float* dst = Wt + (size_t)blockIdx.y * HH * DD;
  const int ty0 = (blockIdx.x >> 2) * 32, tx0 = (blockIdx.x & 3) * 32;
  const int tx = threadIdx.x & 31, ty = threadIdx.x >> 5;
#pragma unroll
  for (int j = 0; j < 32; j += 8)
    t[ty + j][tx] = src[(size_t)(ty0 + ty + j) * DD + tx0 + tx];
  __syncthreads();
#pragma unroll
  for (int j = 0; j < 32; j += 8)
    dst[(size_t)(tx0 + ty + j) * HH + ty0 + tx] = t[tx][ty + j];
}

// ---------------------------------------------------------------------------
// Projection: act[p][row][h] = act_p( sum_d X[row][d] * Wt_p[d][h] + b_p[h] )
// grid (BT_/32, 6), block 256. Thread = 2 rows x 8 h. Planar float4 stores.
// ---------------------------------------------------------------------------
__global__ __launch_bounds__(256)
void proj_kernel(const float* __restrict__ X, const float* __restrict__ Wtl,
                 BArgs args, float* __restrict__ act) {
  __shared__ float xs[32][132];
  const int p = blockIdx.y;
  const int row0 = blockIdx.x * 32;
  const int tid = threadIdx.x;
  {
    const float4* xg = (const float4*)(X + (size_t)row0 * DD);
#pragma unroll
    for (int i = 0; i < 4; ++i) {
      int u = tid + 256 * i;
      float4 v = xg[u];
      *(float4*)&xs[u >> 5][(u & 31) * 4] = v;
    }
  }
  __syncthreads();

  const int h0 = (tid & 15) * 8;
  const int r0 = (tid >> 4) * 2;
  const float* wtp = Wtl + (size_t)p * HH * DD;

  float acc[2][8];
#pragma unroll
  for (int r = 0; r < 2; ++r)
#pragma unroll
    for (int j = 0; j < 8; ++j) acc[r][j] = 0.f;

#pragma unroll 2
  for (int d0 = 0; d0 < DD; d0 += 4) {
    float4 wa[4], wb[4];
#pragma unroll
    for (int i = 0; i < 4; ++i) {
      wa[i] = *(const float4*)(wtp + (size_t)(d0 + i) * HH + h0);
      wb[i] = *(const float4*)(wtp + (size_t)(d0 + i) * HH + h0 + 4);
    }
    float4 x0 = *(const float4*)&xs[r0][d0];
    float4 x1 = *(const float4*)&xs[r0 + 1][d0];
    const float xa[4] = {x0.x, x0.y, x0.z, x0.w};
    const float xb[4] = {x1.x, x1.y, x1.z, x1.w};
#pragma unroll
    for (int i = 0; i < 4; ++i) {
      acc[0][0] = fmaf(xa[i], wa[i].x, acc[0][0]);
      acc[0][1] = fmaf(xa[i], wa[i].y, acc[0][1]);
      acc[0][2] = fmaf(xa[i], wa[i].z, acc[0][2]);
      acc[0][3] = fmaf(xa[i], wa[i].w, acc[0][3]);
      acc[0][4] = fmaf(xa[i], wb[i].x, acc[0][4]);
      acc[0][5] = fmaf(xa[i], wb[i].y, acc[0][5]);
      acc[0][6] = fmaf(xa[i], wb[i].z, acc[0][6]);
      acc[0][7] = fmaf(xa[i], wb[i].w, acc[0][7]);
      acc[1][0] = fmaf(xb[i], wa[i].x, acc[1][0]);
      acc[1][1] = fmaf(xb[i], wa[i].y, acc[1][1]);
      acc[1][2] = fmaf(xb[i], wa[i].z, acc[1][2]);
      acc[1][3] = fmaf(xb[i], wa[i].w, acc[1][3]);
      acc[1][4] = fmaf(xb[i], wb[i].x, acc[1][4]);
      acc[1][5] = fmaf(xb[i], wb[i].y, acc[1][5]);
      acc[1][6] = fmaf(xb[i], wb[i].z, acc[1][6]);
      acc[1][7] = fmaf(xb[i], wb[i].w, acc[1][7]);
    }
  }

  const float4 b0 = *(const float4*)(args.b[p] + h0);
  const float4 b1 = *(const float4*)(args.b[p] + h0 + 4);
  const float bias[8] = {b0.x, b0.y, b0.z, b0.w, b1.x, b1.y, b1.z, b1.w};
#pragma unroll
  for (int r = 0; r < 2; ++r) {
    const size_t row = (size_t)row0 + r0 + r;
    float v[8];
#pragma unroll
    for (int j = 0; j < 8; ++j) {
      float a = acc[r][j] + bias[j];
      if (p == 1)      a *= 0.088388347648318447f;   // 1/sqrt(128)
      else if (p == 3) a = __expf(a);
      else if (p >= 4) a = 1.0f / (1.0f + __expf(-a));
      v[j] = a;
    }
    float* dst = act + (size_t)p * BTH + row * HH + h0;
    *(float4*)dst = make_float4(v[0], v[1], v[2], v[3]);
    *(float4*)(dst + 4) = make_float4(v[4], v[5], v[6], v[7]);
  }
}

// ---------------------------------------------------------------------------
// Scan: sequential over T. 256 single-wave blocks; b = blockIdx&7 (XCD-local).
// DEPTH-8 REGISTER PREFETCH: __launch_bounds__(64,1) lifts the VGPR cap to
// ~512 so 8 live Step buffers (~192 VGPRs) stay in registers — round 4's
// default bounds capped at 76 VGPRs and the compiler re-sank the loads.
// Lane: r=lane>>4 -> row sl*4+r; g=lane&15 -> cols 8g..8g+8 (C[8]).
// n owned at cols 2*lane, 2*lane+1. h uses OLD C, OLD n (per reference).
// Tail prefetch over-reads rows 512..519 -> lands in hbuf region, unused.
// ---------------------------------------------------------------------------
#define PF 8

struct Step {
  float4 q0, q1, k0, k1;     // row slice cols 8g..8g+8
  float2 qn, kn, in2, fn2;   // n-cols 2*lane
  float ir, fr, vr, og;      // broadcast scalars at irow
};                           // 24 floats

__global__ __launch_bounds__(64, 1)
void scan_kernel(const float* __restrict__ act, float* __restrict__ hout) {
  const int lane = threadIdx.x;
  const int b = blockIdx.x & 7;
  const int sl = blockIdx.x >> 3;
  const int r = lane >> 4;
  const int g = lane & 15;
  const int irow = sl * 4 + r;
  const size_t boff = (size_t)b * TT * HH;
  const float* qp = act + boff;
  const float* kp = act + BTH + boff;
  const float* vp = act + 2 * BTH + boff;
  const float* ip = act + 3 * BTH + boff;
  const float* fp = act + 4 * BTH + boff;
  const float* op = act + 5 * BTH + boff;

  float C[8];
#pragma unroll
  for (int c = 0; c < 8; ++c) C[c] = 0.f;
  float nx = 0.f, ny = 0.f;

  auto load_step = [&](int t, Step& S) {
    const int base = t * HH;
    S.q0 = *(const float4*)(qp + base + 8 * g);
    S.q1 = *(const float4*)(qp + base + 8 * g + 4);
    S.k0 = *(const float4*)(kp + base + 8 * g);
    S.k1 = *(const float4*)(kp + base + 8 * g + 4);
    S.qn = *(const float2*)(qp + base + 2 * lane);
    S.kn = *(const float2*)(kp + base + 2 * lane);
    S.in2 = *(const float2*)(ip + base + 2 * lane);
    S.fn2 = *(const float2*)(fp + base + 2 * lane);
    S.ir = ip[base + irow];
    S.fr = fp[base + irow];
    S.vr = vp[base + irow];
    S.og = op[base + irow];
  };

  auto compute = [&](int t, const Step& S) {
    // denom from OLD n: 64-lane DPP sum -> lane 63 -> SGPR broadcast
    float dp = fmaf(nx, S.qn.x, ny * S.qn.y);
    dp = dpp_add<0x111>(dp);  // row_shr:1
    dp = dpp_add<0x112>(dp);  // row_shr:2
    dp = dpp_add<0x114>(dp);  // row_shr:4
    dp = dpp_add<0x118>(dp);  // row_shr:8
    dp = dpp_add<0x142>(dp);  // row_bcast:15
    dp = dpp_add<0x143>(dp);  // row_bcast:31
    const float dpv = __builtin_bit_cast(
        float, __builtin_amdgcn_readlane(__builtin_bit_cast(int, dp), 63));
    const float inv = __builtin_amdgcn_rcpf(fmaxf(fabsf(dpv), 1.0f));

    // h_tilde from OLD C: sum over 16 col-lanes -> lane g==15
    float acc = 0.f;
    acc = fmaf(C[0], S.q0.x, acc); acc = fmaf(C[1], S.q0.y, acc);
    acc = fmaf(C[2], S.q0.z, acc); acc = fmaf(C[3], S.q0.w, acc);
    acc = fmaf(C[4], S.q1.x, acc); acc = fmaf(C[5], S.q1.y, acc);
    acc = fmaf(C[6], S.q1.z, acc); acc = fmaf(C[7], S.q1.w, acc);
    acc = dpp_add<0x111>(acc);
    acc = dpp_add<0x112>(acc);
    acc = dpp_add<0x114>(acc);
    acc = dpp_add<0x118>(acc);
    if (g == 15)
      hout[((size_t)b * TT + t) * HH + irow] = S.og * acc * inv;

    // n update
    nx = fmaf(S.fn2.x, nx, S.in2.x * S.kn.x);
    ny = fmaf(S.fn2.y, ny, S.in2.y * S.kn.y);

    // C update: C = f[row]*C + (i[row]*v[row])*k[col]
    const float ar = S.ir * S.vr;
    C[0] = fmaf(S.fr, C[0], ar * S.k0.x); C[1] = fmaf(S.fr, C[1], ar * S.k0.y);
    C[2] = fmaf(S.fr, C[2], ar * S.k0.z); C[3] = fmaf(S.fr, C[3], ar * S.k0.w);
    C[4] = fmaf(S.fr, C[4], ar * S.k1.x); C[5] = fmaf(S.fr, C[5], ar * S.k1.y);
    C[6] = fmaf(S.fr, C[6], ar * S.k1.z); C[7] = fmaf(S.fr, C[7], ar * S.k1.w);
  };

  Step S[PF];
#pragma unroll
  for (int i = 0; i < PF; ++i) load_step(i, S[i]);

#pragma unroll 1
  for (int t = 0; t < TT; t += PF) {
    compute(t + 0, S[0]); load_step(t + PF + 0, S[0]);
    compute(t + 1, S[1]); load_step(t + PF + 1, S[1]);
    compute(t + 2, S[2]); load_step(t + PF + 2, S[2]);
    compute(t + 3, S[3]); load_step(t + PF + 3, S[3]);
    compute(t + 4, S[4]); load_step(t + PF + 4, S[4]);
    compute(t + 5, S[5]); load_step(t + PF + 5, S[5]);
    compute(t + 6, S[6]); load_step(t + PF + 6, S[6]);
    compute(t + 7, S[7]); load_step(t + PF + 7, S[7]);
  }
}

// ---------------------------------------------------------------------------
extern "C" void kernel_launch(void* const* d_in, const int* in_sizes, int n_in,
                              void* d_out, int out_size, void* d_ws,
                              size_t ws_size, hipStream_t stream) {
  (void)in_sizes; (void)n_in; (void)out_size; (void)ws_size;
  const float* x = (const float*)d_in[0];
  float* act = (float*)d_ws;            // 6 * BTH floats
  float* hbuf = act + 6 * BTH;          // BTH floats
  float* Wt = (float*)d_out;            // 12*128*128 floats, overwritten later

  WArgs wa;
  for (int j = 0; j < 6; ++j) wa.W[j] = (const float*)d_in[1 + j];
  transpose_w<<<dim3(16, 12), 256, 0, stream>>>(wa, Wt);

  for (int l = 0; l < 2; ++l) {
    BArgs ba;
    for (int j = 0; j < 6; ++j)
      ba.b[j] = (const float*)d_in[7 + j] + (size_t)l * HH;
    const float* wtl = Wt + (size_t)l * 6 * HH * DD;
    const float* xin = (l == 0) ? x : hbuf;
    float* hdst = (l == 0) ? hbuf : (float*)d_out;
    proj_kernel<<<dim3(BT_ / 32, 6), 256, 0, stream>>>(xin, wtl, ba, act);
    scan_kernel<<<256, 64, 0, stream>>>(act, hdst);
  }
}

// Round 7
// 387.806 us; speedup vs baseline: 1.4432x; 1.0440x over previous
//
#include <hip/hip_runtime.h>
#include <math.h>

// (B, T, D, H, L) = (8, 512, 128, 128, 2). All fp32 I/O.
#define BB 8
#define TT 512
#define DD 128
#define HH 128
#define BT_ (BB * TT)                 // 4096
static const size_t BTH = (size_t)BT_ * HH;  // 524288

// ws layout (floats): qk-pack [0, 2*BTH)  : [row][2h+{0:q,1:k}]
//                     if-pack [2B, 4*BTH) : [row][2h+{0:i,1:f}]
//                     vo-pack [4B, 6*BTH) : [row][2h+{0:v,1:o}]
//                     hbuf    [6*BTH, 7*BTH) planar [row][h]
// Wt (12x128x128, Wt[l*6+p][d][h]) lives in d_out's first 196608 floats;
// consumed by both proj dispatches, then overwritten by the final scan.

struct BArgs { const float* b[6]; };
struct WArgs { const float* W[6]; };

template <int CTRL>
__device__ __forceinline__ float dpp_add(float x) {
  int y = __builtin_amdgcn_update_dpp(0, __builtin_bit_cast(int, x), CTRL,
                                      0xF, 0xF, true);
  return x + __builtin_bit_cast(float, y);
}

// ---------------------------------------------------------------------------
// Transpose all 12 weight slabs: Wt[l*6+p][d][h] = W_p[l][h][d].
// ---------------------------------------------------------------------------
__global__ __launch_bounds__(256)
void transpose_w(WArgs w, float* __restrict__ Wt) {
  __shared__ float t[32][33];
  const int l = blockIdx.y / 6, p = blockIdx.y % 6;
  const float* src = w.W[p] + (size_t)l * HH * DD;
  float* dst = Wt + (size_t)blockIdx.y * HH * DD;
  const int ty0 = (blockIdx.x >> 2) * 32, tx0 = (blockIdx.x & 3) * 32;
  const int tx = threadIdx.x & 31, ty = threadIdx.x >> 5;
#pragma unroll
  for (int j = 0; j < 32; j += 8)
    t[ty + j][tx] = src[(size_t)(ty0 + ty + j) * DD + tx0 + tx];
  __syncthreads();
#pragma unroll
  for (int j = 0; j < 32; j += 8)
    dst[(size_t)(tx0 + ty + j) * HH + ty0 + tx] = t[tx][ty + j];
}

// ---------------------------------------------------------------------------
// Dual projection: each block computes TWO projections (A,B) for 16 rows and
// stores the interleaved pair plane [row][2h+{0:A,1:B}].
// grid (BT_/16, 3): y=0 -> {q, k*scale}; y=1 -> {exp(i), sigm(f)};
//                   y=2 -> {v, sigm(o)}.  block 256: thread = 1 row x 8h x 2.
// ---------------------------------------------------------------------------
__global__ __launch_bounds__(256)
void proj_kernel(const float* __restrict__ X, const float* __restrict__ Wtl,
                 BArgs args, float* __restrict__ act) {
  __shared__ float xs[16][132];
  const int y = blockIdx.y;
  const int row0 = blockIdx.x * 16;
  const int tid = threadIdx.x;
  {
    const float4* xg = (const float4*)(X + (size_t)row0 * DD);
#pragma unroll
    for (int i = 0; i < 2; ++i) {
      int u = tid + 256 * i;  // float4 index in 16x128 tile
      float4 v = xg[u];
      *(float4*)&xs[u >> 5][(u & 31) * 4] = v;
    }
  }
  __syncthreads();

  const int idxA = (y == 0) ? 0 : (y == 1) ? 3 : 2;
  const int idxB = (y == 0) ? 1 : (y == 1) ? 4 : 5;
  const int h0 = (tid & 15) * 8;
  const int r = tid >> 4;
  const float* wA = Wtl + (size_t)idxA * HH * DD + h0;
  const float* wB = Wtl + (size_t)idxB * HH * DD + h0;
  const float* xr = &xs[r][0];

  float aA[8], aB[8];
#pragma unroll
  for (int j = 0; j < 8; ++j) { aA[j] = 0.f; aB[j] = 0.f; }

#pragma unroll 2
  for (int d0 = 0; d0 < DD; d0 += 4) {
    float4 wa0[4], wa1[4], wb0[4], wb1[4];
#pragma unroll
    for (int i = 0; i < 4; ++i) {
      wa0[i] = *(const float4*)(wA + (size_t)(d0 + i) * HH);
      wa1[i] = *(const float4*)(wA + (size_t)(d0 + i) * HH + 4);
      wb0[i] = *(const float4*)(wB + (size_t)(d0 + i) * HH);
      wb1[i] = *(const float4*)(wB + (size_t)(d0 + i) * HH + 4);
    }
    const float4 xv = *(const float4*)(xr + d0);
    const float xd[4] = {xv.x, xv.y, xv.z, xv.w};
#pragma unroll
    for (int i = 0; i < 4; ++i) {
      aA[0] = fmaf(xd[i], wa0[i].x, aA[0]);
      aA[1] = fmaf(xd[i], wa0[i].y, aA[1]);
      aA[2] = fmaf(xd[i], wa0[i].z, aA[2]);
      aA[3] = fmaf(xd[i], wa0[i].w, aA[3]);
      aA[4] = fmaf(xd[i], wa1[i].x, aA[4]);
      aA[5] = fmaf(xd[i], wa1[i].y, aA[5]);
      aA[6] = fmaf(xd[i], wa1[i].z, aA[6]);
      aA[7] = fmaf(xd[i], wa1[i].w, aA[7]);
      aB[0] = fmaf(xd[i], wb0[i].x, aB[0]);
      aB[1] = fmaf(xd[i], wb0[i].y, aB[1]);
      aB[2] = fmaf(xd[i], wb0[i].z, aB[2]);
      aB[3] = fmaf(xd[i], wb0[i].w, aB[3]);
      aB[4] = fmaf(xd[i], wb1[i].x, aB[4]);
      aB[5] = fmaf(xd[i], wb1[i].y, aB[5]);
      aB[6] = fmaf(xd[i], wb1[i].z, aB[6]);
      aB[7] = fmaf(xd[i], wb1[i].w, aB[7]);
    }
  }

  const float4 bA0 = *(const float4*)(args.b[idxA] + h0);
  const float4 bA1 = *(const float4*)(args.b[idxA] + h0 + 4);
  const float4 bB0 = *(const float4*)(args.b[idxB] + h0);
  const float4 bB1 = *(const float4*)(args.b[idxB] + h0 + 4);
  const float biasA[8] = {bA0.x, bA0.y, bA0.z, bA0.w, bA1.x, bA1.y, bA1.z, bA1.w};
  const float biasB[8] = {bB0.x, bB0.y, bB0.z, bB0.w, bB1.x, bB1.y, bB1.z, bB1.w};

  float vA[8], vB[8];
#pragma unroll
  for (int j = 0; j < 8; ++j) {
    float a = aA[j] + biasA[j];
    float bv = aB[j] + biasB[j];
    if (y == 0) {
      bv *= 0.088388347648318447f;            // k * 1/sqrt(128)
    } else if (y == 1) {
      a = __expf(a);                          // i
      bv = 1.0f / (1.0f + __expf(-bv));       // f
    } else {
      bv = 1.0f / (1.0f + __expf(-bv));       // o (v raw)
    }
    vA[j] = a; vB[j] = bv;
  }

  float* dst = act + (size_t)y * 2 * BTH + (size_t)(row0 + r) * 2 * HH + 2 * h0;
  *(float4*)(dst + 0)  = make_float4(vA[0], vB[0], vA[1], vB[1]);
  *(float4*)(dst + 4)  = make_float4(vA[2], vB[2], vA[3], vB[3]);
  *(float4*)(dst + 8)  = make_float4(vA[4], vB[4], vA[5], vB[5]);
  *(float4*)(dst + 12) = make_float4(vA[6], vB[6], vA[7], vB[7]);
}

// ---------------------------------------------------------------------------
// Scan: sequential over T. 256 single-wave blocks; b = blockIdx&7 (XCD-local).
// DEPTH-6 register prefetch, 8 loads/step -> max 48 outstanding VMEM ops,
// UNDER the 6-bit vmcnt limit of 63 (round 6's depth8 x 12 = 96 jammed it).
// __launch_bounds__(64,1): 1 wave/CU anyway, VGPRs are free (~200 needed).
// Lane: r=lane>>4 -> row sl*4+r; g=lane&15 -> cols 8g..8g+8 (C[8]).
// n owned at cols 2*lane, 2*lane+1. h uses OLD C, OLD n (per reference).
// ---------------------------------------------------------------------------
#define PF 6

struct Step {
  float q[8], k[8];          // row-slice cols 8g..8g+7 (deinterleaved)
  float2 qn, kn;             // q,k at n-cols 2l, 2l+1
  float2 in2, fn2;           // i,f at n-cols
  float2 ifr, vor;           // {i,f} and {v,o} at irow
};                           // 28 floats, 8 loads

__global__ __launch_bounds__(64, 1)
void scan_kernel(const float* __restrict__ act, float* __restrict__ hout) {
  const int lane = threadIdx.x;
  const int b = blockIdx.x & 7;
  const int sl = blockIdx.x >> 3;
  const int r = lane >> 4;
  const int g = lane & 15;
  const int irow = sl * 4 + r;
  const size_t boff2 = (size_t)b * TT * 2 * HH;
  const float* qk = act + boff2;
  const float* ifp = act + 2 * BTH + boff2;
  const float* vop = act + 4 * BTH + boff2;

  float C[8];
#pragma unroll
  for (int c = 0; c < 8; ++c) C[c] = 0.f;
  float nx = 0.f, ny = 0.f;

  auto load_step = [&](int t, Step& S) {
    const int base = t * 2 * HH;
    const float4 m0 = *(const float4*)(qk + base + 16 * g);
    const float4 m1 = *(const float4*)(qk + base + 16 * g + 4);
    const float4 m2 = *(const float4*)(qk + base + 16 * g + 8);
    const float4 m3 = *(const float4*)(qk + base + 16 * g + 12);
    S.q[0] = m0.x; S.k[0] = m0.y; S.q[1] = m0.z; S.k[1] = m0.w;
    S.q[2] = m1.x; S.k[2] = m1.y; S.q[3] = m1.z; S.k[3] = m1.w;
    S.q[4] = m2.x; S.k[4] = m2.y; S.q[5] = m2.z; S.k[5] = m2.w;
    S.q[6] = m3.x; S.k[6] = m3.y; S.q[7] = m3.z; S.k[7] = m3.w;
    const float4 qkn = *(const float4*)(qk + base + 4 * lane);
    S.qn = make_float2(qkn.x, qkn.z);
    S.kn = make_float2(qkn.y, qkn.w);
    const float4 ifn = *(const float4*)(ifp + base + 4 * lane);
    S.in2 = make_float2(ifn.x, ifn.z);
    S.fn2 = make_float2(ifn.y, ifn.w);
    S.ifr = *(const float2*)(ifp + base + 2 * irow);
    S.vor = *(const float2*)(vop + base + 2 * irow);
  };

  auto compute = [&](int t, const Step& S) {
    // denom from OLD n: 64-lane DPP sum -> lane 63 -> SGPR broadcast
    float dp = fmaf(nx, S.qn.x, ny * S.qn.y);
    dp = dpp_add<0x111>(dp);  // row_shr:1
    dp = dpp_add<0x112>(dp);  // row_shr:2
    dp = dpp_add<0x114>(dp);  // row_shr:4
    dp = dpp_add<0x118>(dp);  // row_shr:8
    dp = dpp_add<0x142>(dp);  // row_bcast:15
    dp = dpp_add<0x143>(dp);  // row_bcast:31
    const float dpv = __builtin_bit_cast(
        float, __builtin_amdgcn_readlane(__builtin_bit_cast(int, dp), 63));
    const float inv = __builtin_amdgcn_rcpf(fmaxf(fabsf(dpv), 1.0f));

    // h_tilde from OLD C: sum over 16 col-lanes -> lane g==15
    float acc = 0.f;
    acc = fmaf(C[0], S.q[0], acc); acc = fmaf(C[1], S.q[1], acc);
    acc = fmaf(C[2], S.q[2], acc); acc = fmaf(C[3], S.q[3], acc);
    acc = fmaf(C[4], S.q[4], acc); acc = fmaf(C[5], S.q[5], acc);
    acc = fmaf(C[6], S.q[6], acc); acc = fmaf(C[7], S.q[7], acc);
    acc = dpp_add<0x111>(acc);
    acc = dpp_add<0x112>(acc);
    acc = dpp_add<0x114>(acc);
    acc = dpp_add<0x118>(acc);
    if (g == 15)
      hout[((size_t)b * TT + t) * HH + irow] = S.vor.y * acc * inv;

    // n update
    nx = fmaf(S.fn2.x, nx, S.in2.x * S.kn.x);
    ny = fmaf(S.fn2.y, ny, S.in2.y * S.kn.y);

    // C update: C = f[row]*C + (i[row]*v[row])*k[col]
    const float ar = S.ifr.x * S.vor.x;
    C[0] = fmaf(S.ifr.y, C[0], ar * S.k[0]);
    C[1] = fmaf(S.ifr.y, C[1], ar * S.k[1]);
    C[2] = fmaf(S.ifr.y, C[2], ar * S.k[2]);
    C[3] = fmaf(S.ifr.y, C[3], ar * S.k[3]);
    C[4] = fmaf(S.ifr.y, C[4], ar * S.k[4]);
    C[5] = fmaf(S.ifr.y, C[5], ar * S.k[5]);
    C[6] = fmaf(S.ifr.y, C[6], ar * S.k[6]);
    C[7] = fmaf(S.ifr.y, C[7], ar * S.k[7]);
  };

  Step S[PF];
#pragma unroll
  for (int i = 0; i < PF; ++i) load_step(i, S[i]);

  // 512 = 6*85 + 2
#pragma unroll 1
  for (int p = 0; p < 85; ++p) {
    const int t = 6 * p;
    compute(t + 0, S[0]); load_step(t + 6, S[0]);
    compute(t + 1, S[1]); load_step(t + 7, S[1]);
    compute(t + 2, S[2]); load_step(t + 8, S[2]);
    compute(t + 3, S[3]); load_step(t + 9, S[3]);
    compute(t + 4, S[4]); load_step(t + 10, S[4]);
    compute(t + 5, S[5]); load_step(t + 11, S[5]);
  }
  compute(510, S[0]);
  compute(511, S[1]);
}

// ---------------------------------------------------------------------------
extern "C" void kernel_launch(void* const* d_in, const int* in_sizes, int n_in,
                              void* d_out, int out_size, void* d_ws,
                              size_t ws_size, hipStream_t stream) {
  (void)in_sizes; (void)n_in; (void)out_size; (void)ws_size;
  const float* x = (const float*)d_in[0];
  float* act = (float*)d_ws;            // 6 * BTH floats (3 packed planes)
  float* hbuf = act + 6 * BTH;          // BTH floats
  float* Wt = (float*)d_out;            // 12*128*128 floats, overwritten later

  WArgs wa;
  for (int j = 0; j < 6; ++j) wa.W[j] = (const float*)d_in[1 + j];
  transpose_w<<<dim3(16, 12), 256, 0, stream>>>(wa, Wt);

  for (int l = 0; l < 2; ++l) {
    BArgs ba;
    for (int j = 0; j < 6; ++j)
      ba.b[j] = (const float*)d_in[7 + j] + (size_t)l * HH;
    const float* wtl = Wt + (size_t)l * 6 * HH * DD;
    const float* xin = (l == 0) ? x : hbuf;
    float* hdst = (l == 0) ? hbuf : (float*)d_out;
    proj_kernel<<<dim3(BT_ / 16, 3), 256, 0, stream>>>(xin, wtl, ba, act);
    scan_kernel<<<256, 64, 0, stream>>>(act, hdst);
  }
}